// Round 1
// baseline (10681.535 us; speedup 1.0000x reference)
//
#include <hip/hip_runtime.h>
#include <math.h>

#define S_DIM 1024
#define B_DIM 4
#define E_DIM 1024
#define H_DIM 16
#define M_DIM 128
#define V_DIM 64

// ---------------- K1: QKV projection ----------------
// q[b,h,s,m] = sum_e x[s,b,e] * wq[h,m,e]   (complex, both operands K-major)
// output cols j: [0,2048) -> q, [2048,4096) -> k, [4096,5120) -> v
__global__ __launch_bounds__(256) void qkv_proj(
    const float* __restrict__ xre, const float* __restrict__ xim,
    const float* __restrict__ wqre, const float* __restrict__ wqim,
    const float* __restrict__ wkre, const float* __restrict__ wkim,
    const float* __restrict__ wvre, const float* __restrict__ wvim,
    float2* __restrict__ qws, float2* __restrict__ kws, float2* __restrict__ vws)
{
    __shared__ float xsr[64][17], xsi[64][17], wsr[64][17], wsi[64][17];
    const int tid = threadIdx.x;
    const int r0 = blockIdx.x * 64;
    const int j0 = blockIdx.y * 64;

    const float *wre, *wim;
    int jw0;
    if (j0 < 2048)      { wre = wqre; wim = wqim; jw0 = j0; }
    else if (j0 < 4096) { wre = wkre; wim = wkim; jw0 = j0 - 2048; }
    else                { wre = wvre; wim = wvim; jw0 = j0 - 4096; }

    const int ty = tid >> 4, tx = tid & 15;
    float accre[4][4] = {}, accim[4][4] = {};

    for (int k0 = 0; k0 < E_DIM; k0 += 16) {
        __syncthreads();
        #pragma unroll
        for (int i = 0; i < 4; ++i) {
            int l = tid + 256 * i;
            int row = l >> 4, kk = l & 15;
            xsr[row][kk] = xre[(r0 + row) * E_DIM + k0 + kk];
            xsi[row][kk] = xim[(r0 + row) * E_DIM + k0 + kk];
            wsr[row][kk] = wre[(jw0 + row) * E_DIM + k0 + kk];
            wsi[row][kk] = wim[(jw0 + row) * E_DIM + k0 + kk];
        }
        __syncthreads();
        #pragma unroll
        for (int kk = 0; kk < 16; ++kk) {
            float ar[4], ai[4], br[4], bi[4];
            #pragma unroll
            for (int ii = 0; ii < 4; ++ii) { ar[ii] = xsr[4*ty+ii][kk]; ai[ii] = xsi[4*ty+ii][kk]; }
            #pragma unroll
            for (int jj = 0; jj < 4; ++jj) { br[jj] = wsr[4*tx+jj][kk]; bi[jj] = wsi[4*tx+jj][kk]; }
            #pragma unroll
            for (int ii = 0; ii < 4; ++ii)
                #pragma unroll
                for (int jj = 0; jj < 4; ++jj) {
                    accre[ii][jj] += ar[ii]*br[jj] - ai[ii]*bi[jj];
                    accim[ii][jj] += ar[ii]*bi[jj] + ai[ii]*br[jj];
                }
        }
    }

    #pragma unroll
    for (int ii = 0; ii < 4; ++ii) {
        int r = r0 + 4*ty + ii;
        int s = r >> 2, b = r & 3;            // r = s*B + b
        #pragma unroll
        for (int jj = 0; jj < 4; ++jj) {
            int j = j0 + 4*tx + jj;
            float2 val = make_float2(accre[ii][jj], accim[ii][jj]);
            if (j < 2048) {
                int h = j >> 7, m = j & 127;
                qws[((b*H_DIM + h)*S_DIM + s)*M_DIM + m] = val;
            } else if (j < 4096) {
                int jl = j - 2048;
                int h = jl >> 7, m = jl & 127;
                kws[((b*H_DIM + h)*S_DIM + s)*M_DIM + m] = val;
            } else {
                int jl = j - 4096;
                int h = jl >> 6, vv = jl & 63;
                vws[((b*H_DIM + h)*S_DIM + s)*V_DIM + vv] = val;
            }
        }
    }
}

// ---------------- K2: flash-style complex attention ----------------
// One block = one (b,h) x 32 query rows. Online softmax state in registers,
// row group = 8 consecutive lanes -> shuffle reductions. K/V share one LDS buf.
__global__ __launch_bounds__(256) void attn_kernel(
    const float2* __restrict__ qws, const float2* __restrict__ kws,
    const float2* __restrict__ vws, float2* __restrict__ updws)
{
    __shared__ float2 qs[32][130];   // pad: stride 260 words -> tq rows hit distinct banks
    __shared__ float2 kv[32][66];    // shared K-half / V buffer; stride 132 words
    __shared__ float  ps[32][33];

    const int tid = threadIdx.x;
    const int qt = blockIdx.x;       // 0..31
    const int bh = blockIdx.y;       // 0..63  (= b*16 + h)
    const int q0 = qt * 32;
    const int tq = tid >> 3;         // q row 0..31
    const int tt = tid & 7;          // lane-in-row 0..7

    // Q tile: 32 rows x 128 complex
    #pragma unroll
    for (int i = 0; i < 16; ++i) {
        int l = tid + 256*i;
        int row = l >> 7, m = l & 127;
        qs[row][m] = qws[(bh*S_DIM + q0 + row)*M_DIM + m];
    }

    float m_run = -INFINITY, l_run = 0.f;
    float2 o[8];
    #pragma unroll
    for (int j = 0; j < 8; ++j) o[j] = make_float2(0.f, 0.f);

    const int qglob = q0 + tq;
    const float scale = 0.088388347648318447f;  // 1/sqrt(128)

    for (int t0 = 0; t0 <= q0; t0 += 32) {
        float accre[4] = {}, accim[4] = {};
        #pragma unroll
        for (int mh = 0; mh < 2; ++mh) {
            __syncthreads();   // prev readers of kv (and Q-load on first iter) done
            #pragma unroll
            for (int i = 0; i < 8; ++i) {
                int l = tid + 256*i;
                int row = l >> 6, mi = l & 63;
                kv[row][mi] = kws[(bh*S_DIM + t0 + row)*M_DIM + mh*64 + mi];
            }
            __syncthreads();
            const float4* q4p = (const float4*)&qs[tq][mh*64];
            #pragma unroll 8
            for (int mi = 0; mi < 32; ++mi) {
                float4 q4 = q4p[mi];   // (re0,im0,re1,im1)
                #pragma unroll
                for (int j = 0; j < 4; ++j) {
                    const float4 k4 = *(const float4*)&kv[tt + 8*j][2*mi];
                    accre[j] += q4.x*k4.x - q4.y*k4.y + q4.z*k4.z - q4.w*k4.w;
                    accim[j] += q4.x*k4.y + q4.y*k4.x + q4.z*k4.w + q4.w*k4.z;
                }
            }
        }

        // amplitude + causal mask + online softmax (register state, shuffle reduce)
        float ampv[4];
        #pragma unroll
        for (int j = 0; j < 4; ++j) {
            int tg = t0 + tt + 8*j;
            float a = sqrtf(accre[j]*accre[j] + accim[j]*accim[j]) * scale;
            ampv[j] = (tg > qglob) ? -INFINITY : a;
        }
        float rowmax = fmaxf(fmaxf(ampv[0], ampv[1]), fmaxf(ampv[2], ampv[3]));
        rowmax = fmaxf(rowmax, __shfl_xor(rowmax, 1));
        rowmax = fmaxf(rowmax, __shfl_xor(rowmax, 2));
        rowmax = fmaxf(rowmax, __shfl_xor(rowmax, 4));
        float new_m = fmaxf(m_run, rowmax);        // finite after first tile (t=0 in range)
        float alpha = __expf(m_run - new_m);       // first tile: exp(-inf)=0
        float psum = 0.f;
        #pragma unroll
        for (int j = 0; j < 4; ++j) {
            float p = __expf(ampv[j] - new_m);
            ps[tq][tt + 8*j] = p;
            psum += p;
        }
        psum += __shfl_xor(psum, 1);
        psum += __shfl_xor(psum, 2);
        psum += __shfl_xor(psum, 4);
        l_run = l_run * alpha + psum;
        m_run = new_m;

        __syncthreads();   // ps visible; K reads done -> reuse kv for V
        #pragma unroll
        for (int i = 0; i < 8; ++i) {
            int l = tid + 256*i;
            int row = l >> 6, vv = l & 63;
            kv[row][vv] = vws[(bh*S_DIM + t0 + row)*V_DIM + vv];
        }
        __syncthreads();

        // P @ V : thread owns v-components tt+8j (j=0..7) of its q row
        #pragma unroll
        for (int j = 0; j < 8; ++j) { o[j].x *= alpha; o[j].y *= alpha; }
        for (int tc = 0; tc < 32; ++tc) {
            float p = ps[tq][tc];
            #pragma unroll
            for (int j = 0; j < 8; ++j) {
                float2 v = kv[tc][tt + 8*j];
                o[j].x += p * v.x;
                o[j].y += p * v.y;
            }
        }
        // loop-top sync protects kv/ps before next tile overwrites
    }

    float invl = 1.0f / l_run;
    int b = bh >> 4, h = bh & 15;
    int s = q0 + tq;
    int r = s * B_DIM + b;
    #pragma unroll
    for (int j = 0; j < 8; ++j) {
        updws[r * E_DIM + h * V_DIM + tt + 8*j] = make_float2(o[j].x * invl, o[j].y * invl);
    }
}

// ---------------- K3: output projection + residual ----------------
// out[s,b,f] = sum_e upd[s,b,e]*wo[e,f] + x[s,b,f]; stacked (re, im)
__global__ __launch_bounds__(256) void out_proj(
    const float2* __restrict__ updws,
    const float* __restrict__ wore, const float* __restrict__ woim,
    const float* __restrict__ xre, const float* __restrict__ xim,
    float* __restrict__ out)
{
    __shared__ float2 us[64][17];
    __shared__ float wsr[16][68], wsi[16][68];
    const int tid = threadIdx.x;
    const int r0 = blockIdx.x * 64;
    const int f0 = blockIdx.y * 64;
    const int ty = tid >> 4, tx = tid & 15;
    float accre[4][4] = {}, accim[4][4] = {};

    for (int k0 = 0; k0 < E_DIM; k0 += 16) {
        __syncthreads();
        #pragma unroll
        for (int i = 0; i < 4; ++i) {
            int l = tid + 256*i;
            int row = l >> 4, kk = l & 15;
            us[row][kk] = updws[(r0 + row)*E_DIM + k0 + kk];
            int kk2 = l >> 6, c = l & 63;
            wsr[kk2][c] = wore[(k0 + kk2)*E_DIM + f0 + c];
            wsi[kk2][c] = woim[(k0 + kk2)*E_DIM + f0 + c];
        }
        __syncthreads();
        #pragma unroll
        for (int kk = 0; kk < 16; ++kk) {
            float2 a[4];
            #pragma unroll
            for (int ii = 0; ii < 4; ++ii) a[ii] = us[4*ty+ii][kk];
            float br[4], bi[4];
            #pragma unroll
            for (int jj = 0; jj < 4; ++jj) { br[jj] = wsr[kk][4*tx+jj]; bi[jj] = wsi[kk][4*tx+jj]; }
            #pragma unroll
            for (int ii = 0; ii < 4; ++ii)
                #pragma unroll
                for (int jj = 0; jj < 4; ++jj) {
                    accre[ii][jj] += a[ii].x*br[jj] - a[ii].y*bi[jj];
                    accim[ii][jj] += a[ii].x*bi[jj] + a[ii].y*br[jj];
                }
        }
    }

    const int SBE = S_DIM * B_DIM * E_DIM;
    #pragma unroll
    for (int ii = 0; ii < 4; ++ii) {
        int r = r0 + 4*ty + ii;
        #pragma unroll
        for (int jj = 0; jj < 4; ++jj) {
            int f = f0 + 4*tx + jj;
            int idx = r * E_DIM + f;
            out[idx]       = accre[ii][jj] + xre[idx];
            out[SBE + idx] = accim[ii][jj] + xim[idx];
        }
    }
}

extern "C" void kernel_launch(void* const* d_in, const int* in_sizes, int n_in,
                              void* d_out, int out_size, void* d_ws, size_t ws_size,
                              hipStream_t stream) {
    const float* xre  = (const float*)d_in[0];
    const float* xim  = (const float*)d_in[1];
    const float* wqre = (const float*)d_in[2];
    const float* wqim = (const float*)d_in[3];
    const float* wkre = (const float*)d_in[4];
    const float* wkim = (const float*)d_in[5];
    const float* wvre = (const float*)d_in[6];
    const float* wvim = (const float*)d_in[7];
    const float* wore = (const float*)d_in[8];
    const float* woim = (const float*)d_in[9];
    float* out = (float*)d_out;

    // workspace: q (8.4M f2) | k (8.4M f2) | v (4.2M f2) | upd (4.2M f2)  = 201 MB
    float2* qws   = (float2*)d_ws;
    float2* kws   = qws + (size_t)B_DIM*H_DIM*S_DIM*M_DIM;
    float2* vws   = kws + (size_t)B_DIM*H_DIM*S_DIM*M_DIM;
    float2* updws = vws + (size_t)B_DIM*H_DIM*S_DIM*V_DIM;

    qkv_proj<<<dim3(64, 80), 256, 0, stream>>>(xre, xim, wqre, wqim, wkre, wkim,
                                               wvre, wvim, qws, kws, vws);
    attn_kernel<<<dim3(32, 64), 256, 0, stream>>>(qws, kws, vws, updws);
    out_proj<<<dim3(64, 16), 256, 0, stream>>>(updws, wore, woim, xre, xim, out);
}

// Round 2
// 2603.489 us; speedup vs baseline: 4.1028x; 4.1028x over previous
//
#include <hip/hip_runtime.h>
#include <math.h>

#define S_DIM 1024
#define B_DIM 4
#define E_DIM 1024
#define H_DIM 16
#define M_DIM 128
#define V_DIM 64

typedef __attribute__((ext_vector_type(8))) short short8;
typedef __attribute__((ext_vector_type(4))) float f32x4;
typedef __attribute__((ext_vector_type(4))) int int4v;

__device__ __forceinline__ unsigned short f2bf(float f) {
    union { float f; unsigned u; } v; v.f = f;
    unsigned r = v.u + 0x7FFFu + ((v.u >> 16) & 1u);   // round-to-nearest-even
    return (unsigned short)(r >> 16);
}

__device__ __forceinline__ float2 unpack_bf2(unsigned u) {
    union { unsigned u; float f; } a, b;
    a.u = u << 16;             // low half = re
    b.u = u & 0xFFFF0000u;     // high half = im
    return make_float2(a.f, b.f);
}

__device__ __forceinline__ void async16(const unsigned short* g, unsigned short* l) {
    __builtin_amdgcn_global_load_lds(
        (const __attribute__((address_space(1))) void*)g,
        (__attribute__((address_space(3))) void*)l,
        16, 0, 0);
}

// ---------------- convert: fp32 (re,im) -> bf16 arrays ----------------
__global__ __launch_bounds__(256) void convert_pair(
    const float* __restrict__ re, const float* __restrict__ im,
    unsigned short* __restrict__ dre, unsigned short* __restrict__ dim_, int n4)
{
    int i = blockIdx.x * 256 + threadIdx.x;
    if (i >= n4) return;
    float4 r = ((const float4*)re)[i];
    float4 m = ((const float4*)im)[i];
    ushort4 ro, mo;
    ro.x = f2bf(r.x); ro.y = f2bf(r.y); ro.z = f2bf(r.z); ro.w = f2bf(r.w);
    mo.x = f2bf(m.x); mo.y = f2bf(m.y); mo.z = f2bf(m.z); mo.w = f2bf(m.w);
    ((ushort4*)dre)[i] = ro;
    ((ushort4*)dim_)[i] = mo;
}

// wo (e,f) -> woT (f,e) bf16
__global__ __launch_bounds__(256) void transpose_wo(
    const float* __restrict__ wore, const float* __restrict__ woim,
    unsigned short* __restrict__ wtre, unsigned short* __restrict__ wtim)
{
    __shared__ float tr[32][33], ti[32][33];
    const int bx = blockIdx.x * 32;   // e range
    const int by = blockIdx.y * 32;   // f range
    const int tx = threadIdx.x & 31, ty = threadIdx.x >> 5;
    for (int i = ty; i < 32; i += 8) {
        tr[i][tx] = wore[(bx + i) * E_DIM + by + tx];
        ti[i][tx] = woim[(bx + i) * E_DIM + by + tx];
    }
    __syncthreads();
    for (int i = ty; i < 32; i += 8) {
        wtre[(by + i) * E_DIM + bx + tx] = f2bf(tr[tx][i]);
        wtim[(by + i) * E_DIM + bx + tx] = f2bf(ti[tx][i]);
    }
}

// ---------------- complex bf16 MFMA GEMM: C = A * B^T ----------------
// A[Mr x 1024], B[Nc x 1024] both K-contiguous bf16 (re,im separate).
// MODE 0: Mr=4096 (s,b), Nc=5120 (q|k|v) -> packed bf16 q/k/v workspace
// MODE 1: Mr=4096, Nc=1024 -> out = acc + x (fp32, stacked re/im)
template<int MODE>
__global__ __launch_bounds__(256) void cgemm(
    const unsigned short* __restrict__ Are, const unsigned short* __restrict__ Aim,
    const unsigned short* __restrict__ Bre, const unsigned short* __restrict__ Bim,
    unsigned int* __restrict__ qout, unsigned int* __restrict__ kout,
    unsigned int* __restrict__ vout,
    const float* __restrict__ xre, const float* __restrict__ xim,
    float* __restrict__ out)
{
    __shared__ unsigned short lds[16384];  // 32 KB: Are|Aim|Bre|Bim tiles [128][32]
    const int tid  = threadIdx.x;
    const int wave = tid >> 6;
    const int lane = tid & 63;
    const int r0 = blockIdx.x * 128;
    const int j0 = blockIdx.y * 128;
    const int wm = (wave >> 1) * 64;
    const int wn = (wave & 1) * 64;

    f32x4 accre[4][4], accim[4][4];
    #pragma unroll
    for (int i = 0; i < 4; ++i)
        #pragma unroll
        for (int j = 0; j < 4; ++j) {
            accre[i][j] = (f32x4){0.f, 0.f, 0.f, 0.f};
            accim[i][j] = (f32x4){0.f, 0.f, 0.f, 0.f};
        }

    const int srow = lane >> 2;          // staging: 4 lanes per 64B row
    const int scol = (lane & 3) * 8;
    const int lrow = lane & 15;          // frag: m/n index
    const int lk   = (lane >> 4) * 8;    // frag: k offset

    for (int k0 = 0; k0 < E_DIM; k0 += 32) {
        __syncthreads();
        #pragma unroll
        for (int c = 0; c < 2; ++c) {
            const int ag = (r0 + c * 64 + wave * 16 + srow) * E_DIM + k0 + scol;
            const int bg = (j0 + c * 64 + wave * 16 + srow) * E_DIM + k0 + scol;
            const int lb = wave * 512 + c * 2048;  // ushort index within tile
            async16(Are + ag, &lds[lb]);
            async16(Aim + ag, &lds[4096 + lb]);
            async16(Bre + bg, &lds[8192 + lb]);
            async16(Bim + bg, &lds[12288 + lb]);
        }
        __syncthreads();

        short8 ar[4], ai[4], ain[4], br[4], bi[4];
        #pragma unroll
        for (int im = 0; im < 4; ++im) {
            const int row = wm + im * 16 + lrow;
            ar[im] = *(const short8*)&lds[row * 32 + lk];
            ai[im] = *(const short8*)&lds[4096 + row * 32 + lk];
            int4v t = *(int4v*)&ai[im];
            t = t ^ (int)0x80008000;       // negate bf16 pair (sign-bit flip)
            ain[im] = *(short8*)&t;
        }
        #pragma unroll
        for (int jn = 0; jn < 4; ++jn) {
            const int row = wn + jn * 16 + lrow;
            br[jn] = *(const short8*)&lds[8192 + row * 32 + lk];
            bi[jn] = *(const short8*)&lds[12288 + row * 32 + lk];
        }
        #pragma unroll
        for (int im = 0; im < 4; ++im)
            #pragma unroll
            for (int jn = 0; jn < 4; ++jn) {
                accre[im][jn] = __builtin_amdgcn_mfma_f32_16x16x32_bf16(ar[im],  br[jn], accre[im][jn], 0, 0, 0);
                accre[im][jn] = __builtin_amdgcn_mfma_f32_16x16x32_bf16(ain[im], bi[jn], accre[im][jn], 0, 0, 0);
                accim[im][jn] = __builtin_amdgcn_mfma_f32_16x16x32_bf16(ar[im],  bi[jn], accim[im][jn], 0, 0, 0);
                accim[im][jn] = __builtin_amdgcn_mfma_f32_16x16x32_bf16(ai[im],  br[jn], accim[im][jn], 0, 0, 0);
            }
    }

    // epilogue: D row = m = (lane>>4)*4+reg, col = n = lane&15  [measured m89/m91]
    #pragma unroll
    for (int im = 0; im < 4; ++im) {
        #pragma unroll
        for (int reg = 0; reg < 4; ++reg) {
            const int r = r0 + wm + im * 16 + (lane >> 4) * 4 + reg;
            #pragma unroll
            for (int jn = 0; jn < 4; ++jn) {
                const int j = j0 + wn + jn * 16 + (lane & 15);
                const float vr = accre[im][jn][reg];
                const float vi = accim[im][jn][reg];
                if (MODE == 0) {
                    const int s = r >> 2, b = r & 3;   // r = s*B + b
                    const unsigned val = (unsigned)f2bf(vr) | ((unsigned)f2bf(vi) << 16);
                    if (j < 2048) {
                        const int h = j >> 7, m = j & 127;
                        qout[((b * H_DIM + h) * S_DIM + s) * M_DIM + m] = val;
                    } else if (j < 4096) {
                        const int jl = j - 2048, h = jl >> 7, m = jl & 127;
                        kout[((b * H_DIM + h) * S_DIM + s) * M_DIM + m] = val;
                    } else {
                        const int jl = j - 4096, h = jl >> 6, vv = jl & 63;
                        vout[((b * H_DIM + h) * S_DIM + s) * V_DIM + vv] = val;
                    }
                } else {
                    const int idx = r * E_DIM + j;
                    out[idx] = vr + xre[idx];
                    out[S_DIM * B_DIM * E_DIM + idx] = vi + xim[idx];
                }
            }
        }
    }
}

// ---------------- K2: flash-style complex attention (packed-bf16 I/O) -----
__global__ __launch_bounds__(256) void attn_kernel(
    const unsigned int* __restrict__ qpk, const unsigned int* __restrict__ kpk,
    const unsigned int* __restrict__ vpk,
    unsigned short* __restrict__ updre, unsigned short* __restrict__ updim)
{
    __shared__ float2 qs[32][130];
    __shared__ float2 kv[32][66];
    __shared__ float  ps[32][33];

    const int tid = threadIdx.x;
    const int qt = blockIdx.x;       // 0..31
    const int bh = blockIdx.y;       // 0..63  (= b*16 + h)
    const int q0 = qt * 32;
    const int tq = tid >> 3;         // q row 0..31
    const int tt = tid & 7;          // lane-in-row 0..7

    #pragma unroll
    for (int i = 0; i < 16; ++i) {
        int l = tid + 256 * i;
        int row = l >> 7, m = l & 127;
        qs[row][m] = unpack_bf2(qpk[(bh * S_DIM + q0 + row) * M_DIM + m]);
    }

    float m_run = -INFINITY, l_run = 0.f;
    float2 o[8];
    #pragma unroll
    for (int j = 0; j < 8; ++j) o[j] = make_float2(0.f, 0.f);

    const int qglob = q0 + tq;
    const float scale = 0.088388347648318447f;  // 1/sqrt(128)

    for (int t0 = 0; t0 <= q0; t0 += 32) {
        float accre[4] = {}, accim[4] = {};
        #pragma unroll
        for (int mh = 0; mh < 2; ++mh) {
            __syncthreads();
            #pragma unroll
            for (int i = 0; i < 8; ++i) {
                int l = tid + 256 * i;
                int row = l >> 6, mi = l & 63;
                kv[row][mi] = unpack_bf2(kpk[(bh * S_DIM + t0 + row) * M_DIM + mh * 64 + mi]);
            }
            __syncthreads();
            const float4* q4p = (const float4*)&qs[tq][mh * 64];
            #pragma unroll 8
            for (int mi = 0; mi < 32; ++mi) {
                float4 q4 = q4p[mi];
                #pragma unroll
                for (int j = 0; j < 4; ++j) {
                    const float4 k4 = *(const float4*)&kv[tt + 8 * j][2 * mi];
                    accre[j] += q4.x * k4.x - q4.y * k4.y + q4.z * k4.z - q4.w * k4.w;
                    accim[j] += q4.x * k4.y + q4.y * k4.x + q4.z * k4.w + q4.w * k4.z;
                }
            }
        }

        float ampv[4];
        #pragma unroll
        for (int j = 0; j < 4; ++j) {
            int tg = t0 + tt + 8 * j;
            float a = sqrtf(accre[j] * accre[j] + accim[j] * accim[j]) * scale;
            ampv[j] = (tg > qglob) ? -INFINITY : a;
        }
        float rowmax = fmaxf(fmaxf(ampv[0], ampv[1]), fmaxf(ampv[2], ampv[3]));
        rowmax = fmaxf(rowmax, __shfl_xor(rowmax, 1));
        rowmax = fmaxf(rowmax, __shfl_xor(rowmax, 2));
        rowmax = fmaxf(rowmax, __shfl_xor(rowmax, 4));
        float new_m = fmaxf(m_run, rowmax);
        float alpha = __expf(m_run - new_m);
        float psum = 0.f;
        #pragma unroll
        for (int j = 0; j < 4; ++j) {
            float p = __expf(ampv[j] - new_m);
            ps[tq][tt + 8 * j] = p;
            psum += p;
        }
        psum += __shfl_xor(psum, 1);
        psum += __shfl_xor(psum, 2);
        psum += __shfl_xor(psum, 4);
        l_run = l_run * alpha + psum;
        m_run = new_m;

        __syncthreads();
        #pragma unroll
        for (int i = 0; i < 8; ++i) {
            int l = tid + 256 * i;
            int row = l >> 6, vv = l & 63;
            kv[row][vv] = unpack_bf2(vpk[(bh * S_DIM + t0 + row) * V_DIM + vv]);
        }
        __syncthreads();

        #pragma unroll
        for (int j = 0; j < 8; ++j) { o[j].x *= alpha; o[j].y *= alpha; }
        for (int tc = 0; tc < 32; ++tc) {
            float p = ps[tq][tc];
            #pragma unroll
            for (int j = 0; j < 8; ++j) {
                float2 v = kv[tc][tt + 8 * j];
                o[j].x += p * v.x;
                o[j].y += p * v.y;
            }
        }
    }

    const float invl = 1.0f / l_run;
    const int b = bh >> 4, h = bh & 15;
    const int r = (q0 + tq) * B_DIM + b;
    #pragma unroll
    for (int j = 0; j < 8; ++j) {
        const int off = r * E_DIM + h * V_DIM + tt + 8 * j;
        updre[off] = f2bf(o[j].x * invl);
        updim[off] = f2bf(o[j].y * invl);
    }
}

extern "C" void kernel_launch(void* const* d_in, const int* in_sizes, int n_in,
                              void* d_out, int out_size, void* d_ws, size_t ws_size,
                              hipStream_t stream) {
    const float* xre  = (const float*)d_in[0];
    const float* xim  = (const float*)d_in[1];
    const float* wqre = (const float*)d_in[2];
    const float* wqim = (const float*)d_in[3];
    const float* wkre = (const float*)d_in[4];
    const float* wkim = (const float*)d_in[5];
    const float* wvre = (const float*)d_in[6];
    const float* wvim = (const float*)d_in[7];
    const float* wore = (const float*)d_in[8];
    const float* woim = (const float*)d_in[9];
    float* out = (float*)d_out;

    // workspace layout (~143 MB)
    char* p = (char*)d_ws;
    unsigned int* qpk = (unsigned int*)p;            p += (size_t)B_DIM*H_DIM*S_DIM*M_DIM*4;
    unsigned int* kpk = (unsigned int*)p;            p += (size_t)B_DIM*H_DIM*S_DIM*M_DIM*4;
    unsigned int* vpk = (unsigned int*)p;            p += (size_t)B_DIM*H_DIM*S_DIM*V_DIM*4;
    unsigned short* updre = (unsigned short*)p;      p += (size_t)S_DIM*B_DIM*E_DIM*2;
    unsigned short* updim = (unsigned short*)p;      p += (size_t)S_DIM*B_DIM*E_DIM*2;
    unsigned short* xbre  = (unsigned short*)p;      p += (size_t)S_DIM*B_DIM*E_DIM*2;
    unsigned short* xbim  = (unsigned short*)p;      p += (size_t)S_DIM*B_DIM*E_DIM*2;
    unsigned short* wbre  = (unsigned short*)p;      p += (size_t)5120*E_DIM*2;
    unsigned short* wbim  = (unsigned short*)p;      p += (size_t)5120*E_DIM*2;
    unsigned short* wtre  = (unsigned short*)p;      p += (size_t)E_DIM*E_DIM*2;
    unsigned short* wtim  = (unsigned short*)p;      p += (size_t)E_DIM*E_DIM*2;

    // bf16 conversion passes
    convert_pair<<<4096, 256, 0, stream>>>(xre, xim, xbre, xbim, 1048576);
    convert_pair<<<2048, 256, 0, stream>>>(wqre, wqim, wbre, wbim, 524288);
    convert_pair<<<2048, 256, 0, stream>>>(wkre, wkim, wbre + 2048*1024, wbim + 2048*1024, 524288);
    convert_pair<<<1024, 256, 0, stream>>>(wvre, wvim, wbre + 4096*1024, wbim + 4096*1024, 262144);
    transpose_wo<<<dim3(32, 32), 256, 0, stream>>>(wore, woim, wtre, wtim);

    // QKV projection (bf16 MFMA)
    cgemm<0><<<dim3(32, 40), 256, 0, stream>>>(xbre, xbim, wbre, wbim,
                                               qpk, kpk, vpk,
                                               nullptr, nullptr, nullptr);
    // attention
    attn_kernel<<<dim3(32, 64), 256, 0, stream>>>(qpk, kpk, vpk, updre, updim);
    // output projection + residual (bf16 MFMA)
    cgemm<1><<<dim3(32, 8), 256, 0, stream>>>(updre, updim, wtre, wtim,
                                              nullptr, nullptr, nullptr,
                                              xre, xim, out);
}

// Round 3
// 622.952 us; speedup vs baseline: 17.1466x; 4.1793x over previous
//
#include <hip/hip_runtime.h>
#include <math.h>

#define S_DIM 1024
#define B_DIM 4
#define E_DIM 1024
#define H_DIM 16
#define M_DIM 128
#define V_DIM 64

typedef __attribute__((ext_vector_type(8))) short short8;
typedef __attribute__((ext_vector_type(4))) float f32x4;
typedef __attribute__((ext_vector_type(4))) int int4v;

__device__ __forceinline__ unsigned short f2bf(float f) {
    union { float f; unsigned u; } v; v.f = f;
    unsigned r = v.u + 0x7FFFu + ((v.u >> 16) & 1u);   // round-to-nearest-even
    return (unsigned short)(r >> 16);
}

__device__ __forceinline__ void async16(const unsigned short* g, unsigned short* l) {
    __builtin_amdgcn_global_load_lds(
        (const __attribute__((address_space(1))) void*)g,
        (__attribute__((address_space(3))) void*)l,
        16, 0, 0);
}

// ---------------- convert: fp32 (re,im) -> bf16 arrays ----------------
__global__ __launch_bounds__(256) void convert_pair(
    const float* __restrict__ re, const float* __restrict__ im,
    unsigned short* __restrict__ dre, unsigned short* __restrict__ dim_, int n4)
{
    int i = blockIdx.x * 256 + threadIdx.x;
    if (i >= n4) return;
    float4 r = ((const float4*)re)[i];
    float4 m = ((const float4*)im)[i];
    ushort4 ro, mo;
    ro.x = f2bf(r.x); ro.y = f2bf(r.y); ro.z = f2bf(r.z); ro.w = f2bf(r.w);
    mo.x = f2bf(m.x); mo.y = f2bf(m.y); mo.z = f2bf(m.z); mo.w = f2bf(m.w);
    ((ushort4*)dre)[i] = ro;
    ((ushort4*)dim_)[i] = mo;
}

// wo (e,f) -> woT (f,e) bf16
__global__ __launch_bounds__(256) void transpose_wo(
    const float* __restrict__ wore, const float* __restrict__ woim,
    unsigned short* __restrict__ wtre, unsigned short* __restrict__ wtim)
{
    __shared__ float tr[32][33], ti[32][33];
    const int bx = blockIdx.x * 32;   // e range
    const int by = blockIdx.y * 32;   // f range
    const int tx = threadIdx.x & 31, ty = threadIdx.x >> 5;
    for (int i = ty; i < 32; i += 8) {
        tr[i][tx] = wore[(bx + i) * E_DIM + by + tx];
        ti[i][tx] = woim[(bx + i) * E_DIM + by + tx];
    }
    __syncthreads();
    for (int i = ty; i < 32; i += 8) {
        wtre[(by + i) * E_DIM + bx + tx] = f2bf(tr[tx][i]);
        wtim[(by + i) * E_DIM + bx + tx] = f2bf(ti[tx][i]);
    }
}

// v planes [bh][t][64] -> v^T planes [bh][v][1024]
__global__ __launch_bounds__(256) void vtrans(
    const unsigned short* __restrict__ vrp, const unsigned short* __restrict__ vip,
    unsigned short* __restrict__ vrt, unsigned short* __restrict__ vit)
{
    __shared__ unsigned short tl[2][64][66];   // pitch 66: bank = (t + v/2) % 32
    const int tid = threadIdx.x;
    const int t0 = blockIdx.x * 64;
    const int bh = blockIdx.y;
    #pragma unroll
    for (int pl = 0; pl < 2; ++pl) {
        const unsigned short* src = pl ? vip : vrp;
        #pragma unroll
        for (int p = 0; p < 2; ++p) {
            const int row = p * 32 + (tid >> 3);
            const int col = (tid & 7) * 8;
            short8 d = *(const short8*)&src[((size_t)bh * S_DIM + t0 + row) * V_DIM + col];
            #pragma unroll
            for (int j = 0; j < 8; ++j) tl[pl][row][col + j] = (unsigned short)d[j];
        }
    }
    __syncthreads();
    #pragma unroll
    for (int pl = 0; pl < 2; ++pl) {
        unsigned short* dst = pl ? vit : vrt;
        #pragma unroll
        for (int p = 0; p < 2; ++p) {
            const int v = p * 32 + (tid >> 3);
            const int tc = (tid & 7) * 8;
            short8 d;
            #pragma unroll
            for (int j = 0; j < 8; ++j) d[j] = (short)tl[pl][tc + j][v];
            *(short8*)&dst[((size_t)bh * V_DIM + v) * S_DIM + t0 + tc] = d;
        }
    }
}

// ---------------- complex bf16 MFMA GEMM: C = A * B^T ----------------
// MODE 0: Mr=4096 (s,b), Nc=5120 (q|k|v) -> bf16 planes qr/qi/kr/ki/vr/vi
// MODE 1: Mr=4096, Nc=1024 -> out = acc + x (fp32, stacked re/im)
template<int MODE>
__global__ __launch_bounds__(256) void cgemm(
    const unsigned short* __restrict__ Are, const unsigned short* __restrict__ Aim,
    const unsigned short* __restrict__ Bre, const unsigned short* __restrict__ Bim,
    unsigned short* __restrict__ qrp, unsigned short* __restrict__ qip,
    unsigned short* __restrict__ krp, unsigned short* __restrict__ kip,
    unsigned short* __restrict__ vrp, unsigned short* __restrict__ vip,
    const float* __restrict__ xre, const float* __restrict__ xim,
    float* __restrict__ out)
{
    __shared__ unsigned short lds[16384];  // 32 KB: Are|Aim|Bre|Bim tiles [128][32]
    const int tid  = threadIdx.x;
    const int wave = tid >> 6;
    const int lane = tid & 63;
    const int r0 = blockIdx.x * 128;
    const int j0 = blockIdx.y * 128;
    const int wm = (wave >> 1) * 64;
    const int wn = (wave & 1) * 64;

    f32x4 accre[4][4], accim[4][4];
    #pragma unroll
    for (int i = 0; i < 4; ++i)
        #pragma unroll
        for (int j = 0; j < 4; ++j) {
            accre[i][j] = (f32x4){0.f, 0.f, 0.f, 0.f};
            accim[i][j] = (f32x4){0.f, 0.f, 0.f, 0.f};
        }

    const int srow = lane >> 2;          // staging: 4 lanes per 64B row
    const int scol = (lane & 3) * 8;
    const int lrow = lane & 15;          // frag: m/n index
    const int lk   = (lane >> 4) * 8;    // frag: k offset

    for (int k0 = 0; k0 < E_DIM; k0 += 32) {
        __syncthreads();
        #pragma unroll
        for (int c = 0; c < 2; ++c) {
            const int ag = (r0 + c * 64 + wave * 16 + srow) * E_DIM + k0 + scol;
            const int bg = (j0 + c * 64 + wave * 16 + srow) * E_DIM + k0 + scol;
            const int lb = wave * 512 + c * 2048;  // ushort index within tile
            async16(Are + ag, &lds[lb]);
            async16(Aim + ag, &lds[4096 + lb]);
            async16(Bre + bg, &lds[8192 + lb]);
            async16(Bim + bg, &lds[12288 + lb]);
        }
        __syncthreads();

        short8 ar[4], ai[4], ain[4], br[4], bi[4];
        #pragma unroll
        for (int im = 0; im < 4; ++im) {
            const int row = wm + im * 16 + lrow;
            ar[im] = *(const short8*)&lds[row * 32 + lk];
            ai[im] = *(const short8*)&lds[4096 + row * 32 + lk];
            int4v t = *(int4v*)&ai[im];
            t = t ^ (int)0x80008000;       // negate bf16 pair (sign-bit flip)
            ain[im] = *(short8*)&t;
        }
        #pragma unroll
        for (int jn = 0; jn < 4; ++jn) {
            const int row = wn + jn * 16 + lrow;
            br[jn] = *(const short8*)&lds[8192 + row * 32 + lk];
            bi[jn] = *(const short8*)&lds[12288 + row * 32 + lk];
        }
        #pragma unroll
        for (int im = 0; im < 4; ++im)
            #pragma unroll
            for (int jn = 0; jn < 4; ++jn) {
                accre[im][jn] = __builtin_amdgcn_mfma_f32_16x16x32_bf16(ar[im],  br[jn], accre[im][jn], 0, 0, 0);
                accre[im][jn] = __builtin_amdgcn_mfma_f32_16x16x32_bf16(ain[im], bi[jn], accre[im][jn], 0, 0, 0);
                accim[im][jn] = __builtin_amdgcn_mfma_f32_16x16x32_bf16(ar[im],  bi[jn], accim[im][jn], 0, 0, 0);
                accim[im][jn] = __builtin_amdgcn_mfma_f32_16x16x32_bf16(ai[im],  br[jn], accim[im][jn], 0, 0, 0);
            }
    }

    // epilogue: D row = (lane>>4)*4+reg, col = lane&15  [measured m89/m91]
    #pragma unroll
    for (int im = 0; im < 4; ++im) {
        #pragma unroll
        for (int reg = 0; reg < 4; ++reg) {
            const int r = r0 + wm + im * 16 + (lane >> 4) * 4 + reg;
            #pragma unroll
            for (int jn = 0; jn < 4; ++jn) {
                const int j = j0 + wn + jn * 16 + (lane & 15);
                const float vr = accre[im][jn][reg];
                const float vi = accim[im][jn][reg];
                if (MODE == 0) {
                    const int s = r >> 2, b = r & 3;   // r = s*B + b
                    if (j < 2048) {
                        const int h = j >> 7, m = j & 127;
                        const size_t off = ((size_t)(b * H_DIM + h) * S_DIM + s) * M_DIM + m;
                        qrp[off] = f2bf(vr); qip[off] = f2bf(vi);
                    } else if (j < 4096) {
                        const int jl = j - 2048, h = jl >> 7, m = jl & 127;
                        const size_t off = ((size_t)(b * H_DIM + h) * S_DIM + s) * M_DIM + m;
                        krp[off] = f2bf(vr); kip[off] = f2bf(vi);
                    } else {
                        const int jl = j - 4096, h = jl >> 6, vv = jl & 63;
                        const size_t off = ((size_t)(b * H_DIM + h) * S_DIM + s) * V_DIM + vv;
                        vrp[off] = f2bf(vr); vip[off] = f2bf(vi);
                    }
                } else {
                    const int idx = r * E_DIM + j;
                    out[idx] = vr + xre[idx];
                    out[S_DIM * B_DIM * E_DIM + idx] = vi + xim[idx];
                }
            }
        }
    }
}

// ---------------- K2: MFMA flash attention ----------------
// block = one (b,h) x 64 q rows; 4 waves x 16 rows; K-tile 64.
__global__ __launch_bounds__(256, 2) void attn_mfma(
    const unsigned short* __restrict__ qr, const unsigned short* __restrict__ qi,
    const unsigned short* __restrict__ kr, const unsigned short* __restrict__ ki,
    const unsigned short* __restrict__ vrt, const unsigned short* __restrict__ vit,
    unsigned short* __restrict__ updre, unsigned short* __restrict__ updim)
{
    // pitches keep ds_read_b128 rows 16B-aligned; 8 lanes/4-bank group = LDS BW floor
    __shared__ __align__(16) unsigned short Ks[2][64][136];  // K tile [plane][t][m] (Q staged here first)
    __shared__ __align__(16) unsigned short Vs[2][64][72];   // V^T tile [plane][v][t]
    __shared__ __align__(16) unsigned short Ps[4][16][72];   // per-wave P [q][t]

    const int tid  = threadIdx.x;
    const int wave = tid >> 6;
    const int lane = tid & 63;
    const int qt = (int)gridDim.x - 1 - blockIdx.x;  // long blocks launch first
    const int bh = blockIdx.y;
    const int q0 = qt * 64;
    const size_t base_qk = (size_t)bh * S_DIM * M_DIM;
    const size_t base_v  = (size_t)bh * V_DIM * S_DIM;

    const int fr = lane & 15;        // frag m/n index
    const int fg = lane >> 4;        // 0..3
    const int fk = fg * 8;           // frag k offset (bf16)

    // ---- stage Q tile into Ks, extract per-wave A-frags to registers ----
    #pragma unroll
    for (int pl = 0; pl < 2; ++pl) {
        const unsigned short* src = pl ? qi : qr;
        #pragma unroll
        for (int p = 0; p < 4; ++p) {
            const int row = p * 16 + (tid >> 4);
            const int col = (tid & 15) * 8;
            *(short8*)&Ks[pl][row][col] =
                *(const short8*)&src[base_qk + (size_t)(q0 + row) * M_DIM + col];
        }
    }
    __syncthreads();
    short8 Aqr[4], Aqi[4], Aqin[4];
    {
        const int qrow = wave * 16 + fr;
        #pragma unroll
        for (int ks = 0; ks < 4; ++ks) {
            Aqr[ks] = *(const short8*)&Ks[0][qrow][ks * 32 + fk];
            Aqi[ks] = *(const short8*)&Ks[1][qrow][ks * 32 + fk];
            int4v t = *(int4v*)&Aqi[ks];
            t = t ^ (int)0x80008000;
            Aqin[ks] = *(short8*)&t;
        }
    }

    f32x4 Ore[4], Oim[4];
    #pragma unroll
    for (int vt = 0; vt < 4; ++vt) {
        Ore[vt] = (f32x4){0.f, 0.f, 0.f, 0.f};
        Oim[vt] = (f32x4){0.f, 0.f, 0.f, 0.f};
    }
    float mrun[4] = {-INFINITY, -INFINITY, -INFINITY, -INFINITY};
    float lrun[4] = {0.f, 0.f, 0.f, 0.f};

    const float scale = 0.088388347648318447f;  // 1/sqrt(128)
    const int qbase = q0 + wave * 16 + fg * 4;  // + reg = global q row

    for (int t0 = 0; t0 <= q0; t0 += 64) {
        __syncthreads();   // prior readers of Ks/Vs done (iter0: Q frags extracted)
        // ---- stage K tile (2 planes x 64 x 128) ----
        #pragma unroll
        for (int pl = 0; pl < 2; ++pl) {
            const unsigned short* src = pl ? ki : kr;
            #pragma unroll
            for (int p = 0; p < 4; ++p) {
                const int row = p * 16 + (tid >> 4);
                const int col = (tid & 15) * 8;
                *(short8*)&Ks[pl][row][col] =
                    *(const short8*)&src[base_qk + (size_t)(t0 + row) * M_DIM + col];
            }
        }
        // ---- stage V^T tile (2 planes x 64v x 64t) ----
        #pragma unroll
        for (int pl = 0; pl < 2; ++pl) {
            const unsigned short* src = pl ? vit : vrt;
            #pragma unroll
            for (int p = 0; p < 2; ++p) {
                const int v = p * 32 + (tid >> 3);
                const int col = (tid & 7) * 8;
                *(short8*)&Vs[pl][v][col] =
                    *(const short8*)&src[base_v + (size_t)v * S_DIM + t0 + col];
            }
        }
        __syncthreads();

        // ---- QK^T (complex) into S fragments ----
        f32x4 Sre[4], Sim[4];
        #pragma unroll
        for (int tt = 0; tt < 4; ++tt) {
            Sre[tt] = (f32x4){0.f, 0.f, 0.f, 0.f};
            Sim[tt] = (f32x4){0.f, 0.f, 0.f, 0.f};
            const int trow = tt * 16 + fr;
            short8 Bkr[4], Bki[4];
            #pragma unroll
            for (int ks = 0; ks < 4; ++ks) {
                Bkr[ks] = *(const short8*)&Ks[0][trow][ks * 32 + fk];
                Bki[ks] = *(const short8*)&Ks[1][trow][ks * 32 + fk];
            }
            #pragma unroll
            for (int ks = 0; ks < 4; ++ks) {
                Sre[tt] = __builtin_amdgcn_mfma_f32_16x16x32_bf16(Aqr[ks],  Bkr[ks], Sre[tt], 0, 0, 0);
                Sre[tt] = __builtin_amdgcn_mfma_f32_16x16x32_bf16(Aqin[ks], Bki[ks], Sre[tt], 0, 0, 0);
                Sim[tt] = __builtin_amdgcn_mfma_f32_16x16x32_bf16(Aqr[ks],  Bki[ks], Sim[tt], 0, 0, 0);
                Sim[tt] = __builtin_amdgcn_mfma_f32_16x16x32_bf16(Aqi[ks],  Bkr[ks], Sim[tt], 0, 0, 0);
            }
        }

        // ---- amplitude + causal mask + online softmax (register state) ----
        float amp[4][4];
        #pragma unroll
        for (int tt = 0; tt < 4; ++tt) {
            const int tg = t0 + tt * 16 + fr;
            #pragma unroll
            for (int r = 0; r < 4; ++r) {
                const float re = Sre[tt][r], im = Sim[tt][r];
                const float a = sqrtf(re * re + im * im) * scale;
                amp[tt][r] = (tg > qbase + r) ? -INFINITY : a;
            }
        }
        float al[4];
        #pragma unroll
        for (int r = 0; r < 4; ++r) {
            float rm = fmaxf(fmaxf(amp[0][r], amp[1][r]), fmaxf(amp[2][r], amp[3][r]));
            rm = fmaxf(rm, __shfl_xor(rm, 1));
            rm = fmaxf(rm, __shfl_xor(rm, 2));
            rm = fmaxf(rm, __shfl_xor(rm, 4));
            rm = fmaxf(rm, __shfl_xor(rm, 8));
            const float nm = fmaxf(mrun[r], rm);
            al[r] = __expf(mrun[r] - nm);
            mrun[r] = nm;
            float psum = 0.f;
            #pragma unroll
            for (int tt = 0; tt < 4; ++tt) {
                const float p = __expf(amp[tt][r] - nm);
                psum += p;
                Ps[wave][fg * 4 + r][tt * 16 + fr] = f2bf(p);
            }
            psum += __shfl_xor(psum, 1);
            psum += __shfl_xor(psum, 2);
            psum += __shfl_xor(psum, 4);
            psum += __shfl_xor(psum, 8);
            lrun[r] = lrun[r] * al[r] + psum;
        }
        #pragma unroll
        for (int vt = 0; vt < 4; ++vt)
            #pragma unroll
            for (int r = 0; r < 4; ++r) { Ore[vt][r] *= al[r]; Oim[vt][r] *= al[r]; }

        // ---- PV: P (A-layout via per-wave LDS) x V^T fragments ----
        short8 Pa0 = *(const short8*)&Ps[wave][fr][fk];
        short8 Pa1 = *(const short8*)&Ps[wave][fr][32 + fk];
        #pragma unroll
        for (int vt = 0; vt < 4; ++vt) {
            const int vrow = vt * 16 + fr;
            short8 B0r = *(const short8*)&Vs[0][vrow][fk];
            short8 B1r = *(const short8*)&Vs[0][vrow][32 + fk];
            short8 B0i = *(const short8*)&Vs[1][vrow][fk];
            short8 B1i = *(const short8*)&Vs[1][vrow][32 + fk];
            Ore[vt] = __builtin_amdgcn_mfma_f32_16x16x32_bf16(Pa0, B0r, Ore[vt], 0, 0, 0);
            Ore[vt] = __builtin_amdgcn_mfma_f32_16x16x32_bf16(Pa1, B1r, Ore[vt], 0, 0, 0);
            Oim[vt] = __builtin_amdgcn_mfma_f32_16x16x32_bf16(Pa0, B0i, Oim[vt], 0, 0, 0);
            Oim[vt] = __builtin_amdgcn_mfma_f32_16x16x32_bf16(Pa1, B1i, Oim[vt], 0, 0, 0);
        }
    }

    // ---- epilogue ----
    const int b = bh >> 4, h = bh & 15;
    float inv[4];
    #pragma unroll
    for (int r = 0; r < 4; ++r) inv[r] = 1.0f / lrun[r];
    #pragma unroll
    for (int vt = 0; vt < 4; ++vt) {
        #pragma unroll
        for (int r = 0; r < 4; ++r) {
            const int s = qbase + r;
            const size_t off = ((size_t)(s * B_DIM + b)) * E_DIM + h * V_DIM + vt * 16 + fr;
            updre[off] = f2bf(Ore[vt][r] * inv[r]);
            updim[off] = f2bf(Oim[vt][r] * inv[r]);
        }
    }
}

extern "C" void kernel_launch(void* const* d_in, const int* in_sizes, int n_in,
                              void* d_out, int out_size, void* d_ws, size_t ws_size,
                              hipStream_t stream) {
    const float* xre  = (const float*)d_in[0];
    const float* xim  = (const float*)d_in[1];
    const float* wqre = (const float*)d_in[2];
    const float* wqim = (const float*)d_in[3];
    const float* wkre = (const float*)d_in[4];
    const float* wkim = (const float*)d_in[5];
    const float* wvre = (const float*)d_in[6];
    const float* wvim = (const float*)d_in[7];
    const float* wore = (const float*)d_in[8];
    const float* woim = (const float*)d_in[9];
    float* out = (float*)d_out;

    // workspace layout (~160 MB)
    char* p = (char*)d_ws;
    const size_t QK = (size_t)B_DIM * H_DIM * S_DIM * M_DIM;   // 8.39M
    const size_t VS = (size_t)B_DIM * H_DIM * S_DIM * V_DIM;   // 4.19M
    const size_t SBE = (size_t)S_DIM * B_DIM * E_DIM;          // 4.19M
    unsigned short* qrw = (unsigned short*)p;  p += QK * 2;
    unsigned short* qiw = (unsigned short*)p;  p += QK * 2;
    unsigned short* krw = (unsigned short*)p;  p += QK * 2;
    unsigned short* kiw = (unsigned short*)p;  p += QK * 2;
    unsigned short* vrw = (unsigned short*)p;  p += VS * 2;
    unsigned short* viw = (unsigned short*)p;  p += VS * 2;
    unsigned short* vrt = (unsigned short*)p;  p += VS * 2;
    unsigned short* vit = (unsigned short*)p;  p += VS * 2;
    unsigned short* updre = (unsigned short*)p; p += SBE * 2;
    unsigned short* updim = (unsigned short*)p; p += SBE * 2;
    unsigned short* xbre  = (unsigned short*)p; p += SBE * 2;
    unsigned short* xbim  = (unsigned short*)p; p += SBE * 2;
    unsigned short* wbre  = (unsigned short*)p; p += (size_t)5120 * E_DIM * 2;
    unsigned short* wbim  = (unsigned short*)p; p += (size_t)5120 * E_DIM * 2;
    unsigned short* wtre  = (unsigned short*)p; p += (size_t)E_DIM * E_DIM * 2;
    unsigned short* wtim  = (unsigned short*)p; p += (size_t)E_DIM * E_DIM * 2;

    // bf16 conversion passes
    convert_pair<<<4096, 256, 0, stream>>>(xre, xim, xbre, xbim, 1048576);
    convert_pair<<<2048, 256, 0, stream>>>(wqre, wqim, wbre, wbim, 524288);
    convert_pair<<<2048, 256, 0, stream>>>(wkre, wkim, wbre + 2048*1024, wbim + 2048*1024, 524288);
    convert_pair<<<1024, 256, 0, stream>>>(wvre, wvim, wbre + 4096*1024, wbim + 4096*1024, 262144);
    transpose_wo<<<dim3(32, 32), 256, 0, stream>>>(wore, woim, wtre, wtim);

    // QKV projection (bf16 MFMA) -> separated planes
    cgemm<0><<<dim3(32, 40), 256, 0, stream>>>(xbre, xbim, wbre, wbim,
                                               qrw, qiw, krw, kiw, vrw, viw,
                                               nullptr, nullptr, nullptr);
    // V -> V^T planes
    vtrans<<<dim3(16, 64), 256, 0, stream>>>(vrw, viw, vrt, vit);
    // MFMA flash attention
    attn_mfma<<<dim3(16, 64), 256, 0, stream>>>(qrw, qiw, krw, kiw, vrt, vit, updre, updim);
    // output projection + residual (bf16 MFMA)
    cgemm<1><<<dim3(32, 8), 256, 0, stream>>>(updre, updim, wtre, wtim,
                                              nullptr, nullptr, nullptr, nullptr, nullptr, nullptr,
                                              xre, xim, out);
}